// Round 8
// baseline (27.807 us; speedup 1.0000x reference)
//
#include <hip/hip_runtime.h>
#include <hip/hip_bf16.h>

#define NR 512
#define DF 576

#if __has_builtin(__builtin_amdgcn_exp2f)
#define EXP2F __builtin_amdgcn_exp2f
#else
#define EXP2F exp2f
#endif

typedef short bf16x8 __attribute__((ext_vector_type(8)));
typedef float f32x4 __attribute__((ext_vector_type(4)));

static __device__ __forceinline__ unsigned short f2bf(float f) {
    unsigned int u = __builtin_bit_cast(unsigned int, f);
    unsigned int r = u + 0x7FFFu + ((u >> 16) & 1u);
    return (unsigned short)(r >> 16);
}
static __device__ __forceinline__ float bf2f(unsigned short h) {
    return __builtin_bit_cast(float, ((unsigned int)h) << 16);
}

// Workspace layout (bytes).  Frag-ordered planes:
//  XF[fr(32)][ks(18)][lane(64)][8]  per plane: 294912 u16 = 589824 B
//  WF[w(3)][fc(36)][ks(18)][lane(64)][8] per plane: 995328 u16 = 1990656 B
#define QKV_OFF 0
#define XFH_OFF 3538944
#define XFL_OFF 4128768
#define WFH_OFF 4718592
#define WFL_OFF 6709248
#define WF_PER_W 331776        // elems per w per plane (36*18*64*8)

// ---------------------------------------------------------------------------
// Kernel 0: fp32 -> bf16 hi/lo planes, written in MFMA FRAGMENT ORDER.
// Mapping (m89-verified A/B frag layout for 16x16x32):
//   fr = row>>4, ks = k>>5, lane = (row&15) + 16*((k&31)>>3), j = k&7
// so the GEMM loads operands directly from global, coalesced, no LDS.
// ---------------------------------------------------------------------------
__global__ __launch_bounds__(256) void prep_frag_kernel(
    const float* __restrict__ X,
    const float* __restrict__ Wq, const float* __restrict__ Wk,
    const float* __restrict__ Wv,
    unsigned short* __restrict__ XFh, unsigned short* __restrict__ XFl,
    unsigned short* __restrict__ WFh, unsigned short* __restrict__ WFl)
{
    const int z = blockIdx.y;
    const float* src; unsigned short *dh, *dl; int n4;
    if (z == 0) { src = X; dh = XFh; dl = XFl; n4 = (NR * DF) / 4; }
    else {
        src = (z == 1) ? Wq : (z == 2) ? Wk : Wv;
        dh = WFh + (size_t)(z - 1) * WF_PER_W;
        dl = WFl + (size_t)(z - 1) * WF_PER_W;
        n4 = (DF * DF) / 4;
    }
    const int i = blockIdx.x * 256 + threadIdx.x;
    if (i >= n4) return;
    float4 v = reinterpret_cast<const float4*>(src)[i];

    const int flat = i * 4;                 // row*DF + k  (4 consecutive k)
    const int row  = flat / DF;             // row (X) or col (W)
    const int k    = flat - row * DF;
    const int fr   = row >> 4;
    const int ks   = k >> 5;
    const int lane = (row & 15) + 16 * ((k & 31) >> 3);
    const int off  = ((fr * 18 + ks) * 64 + lane) * 8 + (k & 7);

    ushort4 h, l;
    h.x = f2bf(v.x); l.x = f2bf(v.x - bf2f(h.x));
    h.y = f2bf(v.y); l.y = f2bf(v.y - bf2f(h.y));
    h.z = f2bf(v.z); l.z = f2bf(v.z - bf2f(h.z));
    h.w = f2bf(v.w); l.w = f2bf(v.w - bf2f(h.w));
    *reinterpret_cast<ushort4*>(dh + off) = h;
    *reinterpret_cast<ushort4*>(dl + off) = l;
}

// ---------------------------------------------------------------------------
// Kernel 1: QKV GEMM, LDS-FREE.  864 single-wave blocks; each wave computes
// a 32x32 output tile (2x2 16x16 frags) over full K=576.  Operands stream
// from frag-ordered global planes: 8 coalesced 16B loads + 12 MFMAs per
// k-slice, 3 independent split-term chains (hh, hl, lh) x 4 frag-pairs.
// No LDS, no barriers; compiler software-pipelines the 18-step unroll.
// ---------------------------------------------------------------------------
__global__ __launch_bounds__(64) void qkv_frag_kernel(
    const unsigned short* __restrict__ XFh, const unsigned short* __restrict__ XFl,
    const unsigned short* __restrict__ WFh, const unsigned short* __restrict__ WFl,
    const float* __restrict__ Bq, const float* __restrict__ Bk,
    const float* __restrict__ Bv,
    float* __restrict__ out)
{
    const int bid  = blockIdx.x;            // 864 = 3 * 16 * 18
    const int w    = bid / 288;
    const int rem  = bid - w * 288;
    const int rowt = rem / 18;              // 0..15  (32-row tile)
    const int colt = rem - rowt * 18;       // 0..17  (32-col tile)
    const int lane = threadIdx.x;

    const float* Bi = (w == 0) ? Bq : (w == 1) ? Bk : Bv;
    float* O = out + (size_t)w * NR * DF;
    const unsigned short* wfh = WFh + (size_t)w * WF_PER_W;
    const unsigned short* wfl = WFl + (size_t)w * WF_PER_W;

    // frag base offsets (elems): fr*9216 + ks*512 + lane*8
    const int a0 = (rowt * 2    ) * 9216 + lane * 8;
    const int a1 = (rowt * 2 + 1) * 9216 + lane * 8;
    const int b0 = (colt * 2    ) * 9216 + lane * 8;
    const int b1 = (colt * 2 + 1) * 9216 + lane * 8;

    f32x4 hh[2][2] = {{{0.f,0.f,0.f,0.f},{0.f,0.f,0.f,0.f}},
                      {{0.f,0.f,0.f,0.f},{0.f,0.f,0.f,0.f}}};
    f32x4 hl[2][2] = {{{0.f,0.f,0.f,0.f},{0.f,0.f,0.f,0.f}},
                      {{0.f,0.f,0.f,0.f},{0.f,0.f,0.f,0.f}}};
    f32x4 lh[2][2] = {{{0.f,0.f,0.f,0.f},{0.f,0.f,0.f,0.f}},
                      {{0.f,0.f,0.f,0.f},{0.f,0.f,0.f,0.f}}};

#pragma unroll
    for (int ks = 0; ks < 18; ++ks) {
        const int o = ks * 512;
        bf16x8 ah0 = *reinterpret_cast<const bf16x8*>(XFh + a0 + o);
        bf16x8 ah1 = *reinterpret_cast<const bf16x8*>(XFh + a1 + o);
        bf16x8 al0 = *reinterpret_cast<const bf16x8*>(XFl + a0 + o);
        bf16x8 al1 = *reinterpret_cast<const bf16x8*>(XFl + a1 + o);
        bf16x8 bh0 = *reinterpret_cast<const bf16x8*>(wfh + b0 + o);
        bf16x8 bh1 = *reinterpret_cast<const bf16x8*>(wfh + b1 + o);
        bf16x8 bl0 = *reinterpret_cast<const bf16x8*>(wfl + b0 + o);
        bf16x8 bl1 = *reinterpret_cast<const bf16x8*>(wfl + b1 + o);

        hh[0][0] = __builtin_amdgcn_mfma_f32_16x16x32_bf16(ah0, bh0, hh[0][0], 0, 0, 0);
        hh[0][1] = __builtin_amdgcn_mfma_f32_16x16x32_bf16(ah0, bh1, hh[0][1], 0, 0, 0);
        hh[1][0] = __builtin_amdgcn_mfma_f32_16x16x32_bf16(ah1, bh0, hh[1][0], 0, 0, 0);
        hh[1][1] = __builtin_amdgcn_mfma_f32_16x16x32_bf16(ah1, bh1, hh[1][1], 0, 0, 0);
        hl[0][0] = __builtin_amdgcn_mfma_f32_16x16x32_bf16(ah0, bl0, hl[0][0], 0, 0, 0);
        hl[0][1] = __builtin_amdgcn_mfma_f32_16x16x32_bf16(ah0, bl1, hl[0][1], 0, 0, 0);
        hl[1][0] = __builtin_amdgcn_mfma_f32_16x16x32_bf16(ah1, bl0, hl[1][0], 0, 0, 0);
        hl[1][1] = __builtin_amdgcn_mfma_f32_16x16x32_bf16(ah1, bl1, hl[1][1], 0, 0, 0);
        lh[0][0] = __builtin_amdgcn_mfma_f32_16x16x32_bf16(al0, bh0, lh[0][0], 0, 0, 0);
        lh[0][1] = __builtin_amdgcn_mfma_f32_16x16x32_bf16(al0, bh1, lh[0][1], 0, 0, 0);
        lh[1][0] = __builtin_amdgcn_mfma_f32_16x16x32_bf16(al1, bh0, lh[1][0], 0, 0, 0);
        lh[1][1] = __builtin_amdgcn_mfma_f32_16x16x32_bf16(al1, bh1, lh[1][1], 0, 0, 0);
    }

#pragma unroll
    for (int ni = 0; ni < 2; ++ni) {
        const int col  = colt * 32 + ni * 16 + (lane & 15);
        const float bias = Bi[col];
#pragma unroll
        for (int mi = 0; mi < 2; ++mi) {
            const int row0 = rowt * 32 + mi * 16 + (lane >> 4) * 4;
#pragma unroll
            for (int r = 0; r < 4; ++r)
                O[(size_t)(row0 + r) * DF + col] =
                    ((hh[mi][ni][r] + hl[mi][ni][r]) + lh[mi][ni][r]) + bias;
        }
    }
}

// ---------------------------------------------------------------------------
// Kernel 2: rank-1 attention via tilted-mean interpolation (unchanged R7).
// ---------------------------------------------------------------------------
#define M_NODES 36
#define CHUNKS  16
#define JPC     36
#define CSTRIDE 19

__global__ __launch_bounds__(576) void attn_interp_kernel(
    const float* __restrict__ qkv,
    float* __restrict__ out)
{
    const int n = blockIdx.x;
    const float* Q = qkv + (size_t)n * DF;
    const float* K = qkv + (size_t)(NR + n) * DF;
    const float* V = qkv + (size_t)(2 * NR + n) * DF;

    __shared__ __align__(16) float4 KV4[CHUNKS * CSTRIDE];
    __shared__ __align__(16) float Pf[DF];
    __shared__ __align__(16) float Pg[DF];
    __shared__ float Rt[M_NODES];
    __shared__ float range[2];

    const int t = threadIdx.x;
    const float q = Q[t];
    {
        const int c  = t / JPC;
        const int jl = t - c * JPC;
        float2* dst = reinterpret_cast<float2*>(&KV4[c * CSTRIDE + (jl >> 1)]);
        dst[jl & 1] = make_float2(K[t] * 1.4426950408889634f, V[t]);
    }
    Pf[t] = q;
    __syncthreads();

    if (t < 64) {
        float lo = Pf[t], hi = lo;
#pragma unroll
        for (int r = 1; r < 9; ++r) {
            float v = Pf[t + 64 * r];
            lo = fminf(lo, v); hi = fmaxf(hi, v);
        }
#pragma unroll
        for (int s = 32; s; s >>= 1) {
            lo = fminf(lo, __shfl_xor(lo, s, 64));
            hi = fmaxf(hi, __shfl_xor(hi, s, 64));
        }
        if (t == 0) { range[0] = lo; range[1] = hi; }
    }
    __syncthreads();

    const float qmin = range[0], qmax = range[1];
    const float h    = fmaxf((qmax - qmin) * (1.0f / (M_NODES - 5)), 1e-6f);
    const float qlo  = qmin - 2.0f * h;

    const int m = t >> 4;
    const int c = t & 15;
    const float qm = qlo + h * (float)m;
    const float4* kvp = KV4 + c * CSTRIDE;
    float f0 = 0.f, f1 = 0.f, g0 = 0.f, g1 = 0.f;
#pragma unroll
    for (int jj = 0; jj < JPC / 2; ++jj) {
        float4 p = kvp[jj];
        float e0 = EXP2F(qm * p.x);
        float e1 = EXP2F(qm * p.z);
        g0 += e0; g1 += e1;
        f0 = fmaf(e0, p.y, f0);
        f1 = fmaf(e1, p.w, f1);
    }
    __syncthreads();
    Pf[t] = f0 + f1;
    Pg[t] = g0 + g1;
    __syncthreads();

    if (t < M_NODES) {
        const float4* pf4 = reinterpret_cast<const float4*>(Pf) + t * 4;
        const float4* pg4 = reinterpret_cast<const float4*>(Pg) + t * 4;
        float fs = 0.f, gs = 0.f;
#pragma unroll
        for (int i = 0; i < 4; ++i) {
            float4 a = pf4[i], b = pg4[i];
            fs += (a.x + a.y) + (a.z + a.w);
            gs += (b.x + b.y) + (b.z + b.w);
        }
        Rt[t] = fs / gs;
    }
    __syncthreads();

    const float u = (q - qlo) * (1.0f / h);
    int i0 = (int)u;
    i0 = (i0 < 1) ? 1 : (i0 > M_NODES - 3 ? M_NODES - 3 : i0);
    const float tf = u - (float)i0;
    const float a  = Rt[i0 - 1];
    const float b  = Rt[i0];
    const float cc = Rt[i0 + 1];
    const float d  = Rt[i0 + 2];
    const float m0 = 0.5f * (cc - a);
    const float m1 = 0.5f * (d - b);
    const float dd = cc - b;
    const float r  = b + tf * (m0 + tf * ((3.f * dd - 2.f * m0 - m1)
                                          + tf * (m0 + m1 - 2.f * dd)));
    out[(size_t)n * DF + t] = r;
}

// ---------------------------------------------------------------------------
extern "C" void kernel_launch(void* const* d_in, const int* in_sizes, int n_in,
                              void* d_out, int out_size, void* d_ws, size_t ws_size,
                              hipStream_t stream) {
    const float* x  = (const float*)d_in[0];
    const float* Wq = (const float*)d_in[1];
    const float* bq = (const float*)d_in[2];
    const float* Wk = (const float*)d_in[3];
    const float* bk = (const float*)d_in[4];
    const float* Wv = (const float*)d_in[5];
    const float* bv = (const float*)d_in[6];

    char* ws = (char*)d_ws;
    float*          qkv = (float*)(ws + QKV_OFF);
    unsigned short* XFh = (unsigned short*)(ws + XFH_OFF);
    unsigned short* XFl = (unsigned short*)(ws + XFL_OFF);
    unsigned short* WFh = (unsigned short*)(ws + WFH_OFF);
    unsigned short* WFl = (unsigned short*)(ws + WFL_OFF);

    prep_frag_kernel<<<dim3(324, 4, 1), 256, 0, stream>>>(
        x, Wq, Wk, Wv, XFh, XFl, WFh, WFl);

    qkv_frag_kernel<<<864, 64, 0, stream>>>(
        XFh, XFl, WFh, WFl, bq, bk, bv, qkv);

    attn_interp_kernel<<<NR, DF, 0, stream>>>(qkv, (float*)d_out);
}

// Round 9
// 27.353 us; speedup vs baseline: 1.0166x; 1.0166x over previous
//
#include <hip/hip_runtime.h>
#include <hip/hip_bf16.h>

#define NR 512
#define DF 576

#if __has_builtin(__builtin_amdgcn_exp2f)
#define EXP2F __builtin_amdgcn_exp2f
#else
#define EXP2F exp2f
#endif

typedef short bf16x8 __attribute__((ext_vector_type(8)));
typedef float f32x4 __attribute__((ext_vector_type(4)));
typedef unsigned short u16x8 __attribute__((ext_vector_type(8)));

static __device__ __forceinline__ unsigned short f2bf(float f) {
    unsigned int u = __builtin_bit_cast(unsigned int, f);
    unsigned int r = u + 0x7FFFu + ((u >> 16) & 1u);
    return (unsigned short)(r >> 16);
}
static __device__ __forceinline__ float bf2f(unsigned short h) {
    return __builtin_bit_cast(float, ((unsigned int)h) << 16);
}

// Workspace layout (bytes):
//  PT[kc(3)][w(3)][512][576] fp32 partials : 10,616,832
//  XF planes (frag-ordered bf16 hi/lo)     : 589,824 each
//  WF planes                               : 1,990,656 each
#define PT_OFF  0
#define XFH_OFF 10616832
#define XFL_OFF 11206656
#define WFH_OFF 11796480
#define WFL_OFF 13787136
#define WF_PER_W 331776        // elems per w per plane (36*18*64*8)

// ---------------------------------------------------------------------------
// Kernel 0: fp32 -> bf16 hi/lo planes in MFMA fragment order.
// Thread handles 8 consecutive k -> one 16B write per plane (frag-row).
//   fr=row>>4, ks=k>>5, lane=(row&15)+16*((k&31)>>3), j=k&7
// ---------------------------------------------------------------------------
__global__ __launch_bounds__(256) void prep_frag_kernel(
    const float* __restrict__ X,
    const float* __restrict__ Wq, const float* __restrict__ Wk,
    const float* __restrict__ Wv,
    unsigned short* __restrict__ XFh, unsigned short* __restrict__ XFl,
    unsigned short* __restrict__ WFh, unsigned short* __restrict__ WFl)
{
    const int z = blockIdx.y;
    const float* src; unsigned short *dh, *dl; int n8;
    if (z == 0) { src = X; dh = XFh; dl = XFl; n8 = (NR * DF) / 8; }
    else {
        src = (z == 1) ? Wq : (z == 2) ? Wk : Wv;
        dh = WFh + (size_t)(z - 1) * WF_PER_W;
        dl = WFl + (size_t)(z - 1) * WF_PER_W;
        n8 = (DF * DF) / 8;
    }
    const int i = blockIdx.x * 256 + threadIdx.x;
    if (i >= n8) return;

    const int flat = i * 8;
    const int row  = flat / DF;
    const int k    = flat - row * DF;          // multiple of 8
    const int fr   = row >> 4;
    const int ks   = k >> 5;
    const int lane = (row & 15) + 16 * ((k & 31) >> 3);
    const int off  = ((fr * 18 + ks) * 64 + lane) * 8;

    const float4 v0 = *reinterpret_cast<const float4*>(src + (size_t)row * DF + k);
    const float4 v1 = *reinterpret_cast<const float4*>(src + (size_t)row * DF + k + 4);
    float fv[8] = {v0.x, v0.y, v0.z, v0.w, v1.x, v1.y, v1.z, v1.w};
    u16x8 h, l;
#pragma unroll
    for (int e = 0; e < 8; ++e) {
        unsigned short hh = f2bf(fv[e]);
        h[e] = hh;
        l[e] = f2bf(fv[e] - bf2f(hh));
    }
    *reinterpret_cast<u16x8*>(dh + off) = h;
    *reinterpret_cast<u16x8*>(dl + off) = l;
}

// ---------------------------------------------------------------------------
// Kernel 1: QKV GEMM, LDS-free + SPLIT-K(3).  Grid (9,8,9): x=colt2, y=rowt2,
// z=w*3+kc.  256 thr = 4 waves in 2x2: A/B frags shared pairwise via L1.
// Each wave: 32x32 output tile over K-chunk 192 = 6 slices x {8 b128 loads,
// 12 MFMA in 3 independent split chains}.  2592 waves (10.1/CU), no barriers.
// Partials written without bias; attn reduces them.
// ---------------------------------------------------------------------------
__global__ __launch_bounds__(256) void qkv_splitk_kernel(
    const unsigned short* __restrict__ XFh, const unsigned short* __restrict__ XFl,
    const unsigned short* __restrict__ WFh, const unsigned short* __restrict__ WFl,
    float* __restrict__ PT)
{
    const int w  = blockIdx.z / 3;
    const int kc = blockIdx.z - w * 3;
    const int tid  = threadIdx.x;
    const int lane = tid & 63;
    const int wv   = tid >> 6;
    const int rowt = blockIdx.y * 2 + (wv >> 1);   // 0..15
    const int colt = blockIdx.x * 2 + (wv & 1);    // 0..17

    const unsigned short* wfh = WFh + (size_t)w * WF_PER_W;
    const unsigned short* wfl = WFl + (size_t)w * WF_PER_W;

    const int kbase = kc * 6 * 512;
    const int a0 = (rowt * 2    ) * 9216 + kbase + lane * 8;
    const int a1 = (rowt * 2 + 1) * 9216 + kbase + lane * 8;
    const int b0 = (colt * 2    ) * 9216 + kbase + lane * 8;
    const int b1 = (colt * 2 + 1) * 9216 + kbase + lane * 8;

    f32x4 hh[2][2] = {{{0.f,0.f,0.f,0.f},{0.f,0.f,0.f,0.f}},
                      {{0.f,0.f,0.f,0.f},{0.f,0.f,0.f,0.f}}};
    f32x4 hl[2][2] = {{{0.f,0.f,0.f,0.f},{0.f,0.f,0.f,0.f}},
                      {{0.f,0.f,0.f,0.f},{0.f,0.f,0.f,0.f}}};
    f32x4 lh[2][2] = {{{0.f,0.f,0.f,0.f},{0.f,0.f,0.f,0.f}},
                      {{0.f,0.f,0.f,0.f},{0.f,0.f,0.f,0.f}}};

#pragma unroll
    for (int s = 0; s < 6; ++s) {
        const int o = s * 512;
        bf16x8 ah0 = *reinterpret_cast<const bf16x8*>(XFh + a0 + o);
        bf16x8 ah1 = *reinterpret_cast<const bf16x8*>(XFh + a1 + o);
        bf16x8 al0 = *reinterpret_cast<const bf16x8*>(XFl + a0 + o);
        bf16x8 al1 = *reinterpret_cast<const bf16x8*>(XFl + a1 + o);
        bf16x8 bh0 = *reinterpret_cast<const bf16x8*>(wfh + b0 + o);
        bf16x8 bh1 = *reinterpret_cast<const bf16x8*>(wfh + b1 + o);
        bf16x8 bl0 = *reinterpret_cast<const bf16x8*>(wfl + b0 + o);
        bf16x8 bl1 = *reinterpret_cast<const bf16x8*>(wfl + b1 + o);

        hh[0][0] = __builtin_amdgcn_mfma_f32_16x16x32_bf16(ah0, bh0, hh[0][0], 0, 0, 0);
        hh[0][1] = __builtin_amdgcn_mfma_f32_16x16x32_bf16(ah0, bh1, hh[0][1], 0, 0, 0);
        hh[1][0] = __builtin_amdgcn_mfma_f32_16x16x32_bf16(ah1, bh0, hh[1][0], 0, 0, 0);
        hh[1][1] = __builtin_amdgcn_mfma_f32_16x16x32_bf16(ah1, bh1, hh[1][1], 0, 0, 0);
        hl[0][0] = __builtin_amdgcn_mfma_f32_16x16x32_bf16(ah0, bl0, hl[0][0], 0, 0, 0);
        hl[0][1] = __builtin_amdgcn_mfma_f32_16x16x32_bf16(ah0, bl1, hl[0][1], 0, 0, 0);
        hl[1][0] = __builtin_amdgcn_mfma_f32_16x16x32_bf16(ah1, bl0, hl[1][0], 0, 0, 0);
        hl[1][1] = __builtin_amdgcn_mfma_f32_16x16x32_bf16(ah1, bl1, hl[1][1], 0, 0, 0);
        lh[0][0] = __builtin_amdgcn_mfma_f32_16x16x32_bf16(al0, bh0, lh[0][0], 0, 0, 0);
        lh[0][1] = __builtin_amdgcn_mfma_f32_16x16x32_bf16(al0, bh1, lh[0][1], 0, 0, 0);
        lh[1][0] = __builtin_amdgcn_mfma_f32_16x16x32_bf16(al1, bh0, lh[1][0], 0, 0, 0);
        lh[1][1] = __builtin_amdgcn_mfma_f32_16x16x32_bf16(al1, bh1, lh[1][1], 0, 0, 0);
    }

    float* P = PT + (size_t)(kc * 3 + w) * NR * DF;
#pragma unroll
    for (int ni = 0; ni < 2; ++ni) {
        const int col = colt * 32 + ni * 16 + (lane & 15);
#pragma unroll
        for (int mi = 0; mi < 2; ++mi) {
            const int row0 = rowt * 32 + mi * 16 + (lane >> 4) * 4;
#pragma unroll
            for (int r = 0; r < 4; ++r)
                P[(size_t)(row0 + r) * DF + col] =
                    (hh[mi][ni][r] + hl[mi][ni][r]) + lh[mi][ni][r];
        }
    }
}

// ---------------------------------------------------------------------------
// Kernel 2: rank-1 attention via tilted-mean interpolation; fuses the
// split-K reduction (+bias) while loading Q/K/V.
// ---------------------------------------------------------------------------
#define M_NODES 36
#define CHUNKS  16
#define JPC     36
#define CSTRIDE 19

__global__ __launch_bounds__(576) void attn_interp_kernel(
    const float* __restrict__ PT,
    const float* __restrict__ bq, const float* __restrict__ bk,
    const float* __restrict__ bv,
    float* __restrict__ out)
{
    const int n = blockIdx.x;
    const int t = threadIdx.x;
    const size_t nb = (size_t)n * DF + t;
    const size_t pl = (size_t)NR * DF;

    const float qv = ((PT[nb] + PT[pl * 3 + nb]) + PT[pl * 6 + nb]) + bq[t];
    const float kv = ((PT[pl + nb] + PT[pl * 4 + nb]) + PT[pl * 7 + nb]) + bk[t];
    const float vv = ((PT[pl * 2 + nb] + PT[pl * 5 + nb]) + PT[pl * 8 + nb]) + bv[t];

    __shared__ __align__(16) float4 KV4[CHUNKS * CSTRIDE];
    __shared__ __align__(16) float Pf[DF];
    __shared__ __align__(16) float Pg[DF];
    __shared__ float Rt[M_NODES];
    __shared__ float range[2];

    {
        const int c  = t / JPC;
        const int jl = t - c * JPC;
        float2* dst = reinterpret_cast<float2*>(&KV4[c * CSTRIDE + (jl >> 1)]);
        dst[jl & 1] = make_float2(kv * 1.4426950408889634f, vv);
    }
    Pf[t] = qv;
    __syncthreads();

    if (t < 64) {
        float lo = Pf[t], hi = lo;
#pragma unroll
        for (int r = 1; r < 9; ++r) {
            float v = Pf[t + 64 * r];
            lo = fminf(lo, v); hi = fmaxf(hi, v);
        }
#pragma unroll
        for (int s = 32; s; s >>= 1) {
            lo = fminf(lo, __shfl_xor(lo, s, 64));
            hi = fmaxf(hi, __shfl_xor(hi, s, 64));
        }
        if (t == 0) { range[0] = lo; range[1] = hi; }
    }
    __syncthreads();

    const float qmin = range[0], qmax = range[1];
    const float h    = fmaxf((qmax - qmin) * (1.0f / (M_NODES - 5)), 1e-6f);
    const float qlo  = qmin - 2.0f * h;

    const int m = t >> 4;
    const int c = t & 15;
    const float qm = qlo + h * (float)m;
    const float4* kvp = KV4 + c * CSTRIDE;
    float f0 = 0.f, f1 = 0.f, g0 = 0.f, g1 = 0.f;
#pragma unroll
    for (int jj = 0; jj < JPC / 2; ++jj) {
        float4 p = kvp[jj];
        float e0 = EXP2F(qm * p.x);
        float e1 = EXP2F(qm * p.z);
        g0 += e0; g1 += e1;
        f0 = fmaf(e0, p.y, f0);
        f1 = fmaf(e1, p.w, f1);
    }
    __syncthreads();
    Pf[t] = f0 + f1;
    Pg[t] = g0 + g1;
    __syncthreads();

    if (t < M_NODES) {
        const float4* pf4 = reinterpret_cast<const float4*>(Pf) + t * 4;
        const float4* pg4 = reinterpret_cast<const float4*>(Pg) + t * 4;
        float fs = 0.f, gs = 0.f;
#pragma unroll
        for (int i = 0; i < 4; ++i) {
            float4 a = pf4[i], b = pg4[i];
            fs += (a.x + a.y) + (a.z + a.w);
            gs += (b.x + b.y) + (b.z + b.w);
        }
        Rt[t] = fs / gs;
    }
    __syncthreads();

    const float u = (qv - qlo) * (1.0f / h);
    int i0 = (int)u;
    i0 = (i0 < 1) ? 1 : (i0 > M_NODES - 3 ? M_NODES - 3 : i0);
    const float tf = u - (float)i0;
    const float a  = Rt[i0 - 1];
    const float b  = Rt[i0];
    const float cc = Rt[i0 + 1];
    const float d  = Rt[i0 + 2];
    const float m0 = 0.5f * (cc - a);
    const float m1 = 0.5f * (d - b);
    const float dd = cc - b;
    const float r  = b + tf * (m0 + tf * ((3.f * dd - 2.f * m0 - m1)
                                          + tf * (m0 + m1 - 2.f * dd)));
    out[(size_t)n * DF + t] = r;
}

// ---------------------------------------------------------------------------
extern "C" void kernel_launch(void* const* d_in, const int* in_sizes, int n_in,
                              void* d_out, int out_size, void* d_ws, size_t ws_size,
                              hipStream_t stream) {
    const float* x  = (const float*)d_in[0];
    const float* Wq = (const float*)d_in[1];
    const float* bq = (const float*)d_in[2];
    const float* Wk = (const float*)d_in[3];
    const float* bk = (const float*)d_in[4];
    const float* Wv = (const float*)d_in[5];
    const float* bv = (const float*)d_in[6];

    char* ws = (char*)d_ws;
    float*          PT  = (float*)(ws + PT_OFF);
    unsigned short* XFh = (unsigned short*)(ws + XFH_OFF);
    unsigned short* XFl = (unsigned short*)(ws + XFL_OFF);
    unsigned short* WFh = (unsigned short*)(ws + WFH_OFF);
    unsigned short* WFl = (unsigned short*)(ws + WFL_OFF);

    prep_frag_kernel<<<dim3(162, 4, 1), 256, 0, stream>>>(
        x, Wq, Wk, Wv, XFh, XFl, WFh, WFl);

    qkv_splitk_kernel<<<dim3(9, 8, 9), 256, 0, stream>>>(
        XFh, XFl, WFh, WFl, PT);

    attn_interp_kernel<<<NR, DF, 0, stream>>>(PT, bq, bk, bv, (float*)d_out);
}